// Round 8
// baseline (198.743 us; speedup 1.0000x reference)
//
#include <hip/hip_runtime.h>
#include <hip/hip_bf16.h>

#define DP     257
#define NP     2049
#define NSEQ   2048
#define NB     16
#define KLD    288         // pitch for small matrices (shorts)
#define HROWS  320         // padded rows for Hb
#define TPITCH 320         // Hbt pitch in shorts: 640 B = 5 full 128B lines
#define TROWS  2176        // padded t rows for Hbt (17*128)
#define KPAD   40          // LDS row pitch (shorts) for gram
#define ATKP   34          // LDS row pitch (shorts) for attn: 68 B = 17-dword
                           // stride (odd) -> 16 frag rows = 16 distinct banks

typedef __attribute__((ext_vector_type(8))) short bf16x8;
typedef __attribute__((ext_vector_type(4))) short bf16x4;
typedef __attribute__((ext_vector_type(4))) float f32x4;

// ---------------------------------------------------------------------------
// Fused conversion kernel.
//  z < NB : H -> Hb (row-major bf16, masked H-hat) and Hbt (transposed)
//  z == NB: bx<5 -> Pb[m][k]=P (zero-padded 288x288); bx in 5..9 -> Qt[n][k]=Q[k][n]
// ---------------------------------------------------------------------------
__global__ __launch_bounds__(256) void conv_all(const float* __restrict__ H,
                                                const float* __restrict__ P,
                                                const float* __restrict__ Q,
                                                __hip_bfloat16* __restrict__ Hb,
                                                __hip_bfloat16* __restrict__ Hbt,
                                                __hip_bfloat16* __restrict__ Pb,
                                                __hip_bfloat16* __restrict__ Qt) {
    const int z  = blockIdx.z;
    const int tl = threadIdx.x & 63;
    const int er = threadIdx.x >> 6;
    __shared__ float tile[64][65];

    if (z < NB) {
        const int b  = z;
        const int t0 = blockIdx.x * 64;
        const int e0 = blockIdx.y * 64;
        const float* __restrict__ Hs = H + (size_t)b * DP * NP;
        __hip_bfloat16* __restrict__ Hbb  = Hb  + (size_t)b * HROWS * 2048;
        __hip_bfloat16* __restrict__ Hbtb = Hbt + (size_t)b * TROWS * TPITCH;

#pragma unroll
        for (int r = 0; r < 16; ++r) {
            const int el = er + r * 4;        // 0..63
            const int ge = e0 + el;
            const int gt = t0 + tl;
            float v = 0.f;
            if (ge < DP && gt < NP) v = Hs[(size_t)ge * NP + gt];
            tile[el][tl] = v;
            if (ge < HROWS && gt < 2048) Hbb[(size_t)ge * 2048 + gt] = __float2bfloat16(v);
        }
        __syncthreads();
#pragma unroll
        for (int r = 0; r < 16; ++r) {
            const int ttl = er + r * 4;       // t-local
            const int gt = t0 + ttl;
            const int ge = e0 + tl;           // e-local = lane -> contiguous writes
            if (gt < TROWS && ge < TPITCH) {
                const float v = (ge < KLD) ? tile[tl][ttl] : 0.f;
                Hbtb[(size_t)gt * TPITCH + ge] = __float2bfloat16(v);
            }
        }
        return;
    }

    // z == NB: P/Q conversion (50 blocks ride along)
    const int bx = blockIdx.x;
    if (bx >= 10) return;
    const int r0 = blockIdx.y * 64;
    if (bx < 5) {
        const int c0 = bx * 64;
#pragma unroll
        for (int r = 0; r < 16; ++r) {
            const int m = r0 + er + r * 4;
            const int k = c0 + tl;
            float v = (m < DP && k < DP) ? P[m * DP + k] : 0.f;
            if (m < KLD && k < KLD) Pb[m * KLD + k] = __float2bfloat16(v);
        }
    } else {
        const int c0 = (bx - 5) * 64;
#pragma unroll
        for (int r = 0; r < 16; ++r) {
            const int k = r0 + er + r * 4;
            const int n = c0 + tl;
            float v = (k < DP && n < DP) ? Q[k * DP + n] : 0.f;
            tile[k - r0][n - c0] = v;
        }
        __syncthreads();
#pragma unroll
        for (int r = 0; r < 16; ++r) {
            const int k = r0 + tl;
            const int n = c0 + er + r * 4;
            if (n < KLD && k < KLD) Qt[n * KLD + k] = __float2bfloat16(tile[tl][n - c0]);
        }
    }
}

// ---------------------------------------------------------------------------
// G[b] = Hb[b] @ Hb[b]^T  -- upper-triangle tiles (15 of 25), mirror written
// transposed. 240 blocks, 512 threads, split-K x2 in-block.
// v8: v5-style pipeline -- 2-deep register prefetch, ds_write of chunk kt+1
// after the MFMAs, ONE barrier per chunk, no same-chunk vmcnt stall.
// ---------------------------------------------------------------------------
__global__ __launch_bounds__(512, 4) void gram_staged(const __hip_bfloat16* __restrict__ Hb,
                                                      __hip_bfloat16* __restrict__ G) {
    const int b  = blockIdx.y;
    // enumerate upper-triangle tiles: (0,0)..(0,4),(1,1)..(4,4)
    int idx = blockIdx.x, tm = 0, w = 5;
    while (idx >= w) { idx -= w; ++tm; --w; }
    const int tn = tm + idx;
    const int m0 = tm * 64, n0 = tn * 64;
    const int tid = threadIdx.x;
    const int wave = tid >> 6, lane = tid & 63;
    const int lrow = lane & 15, kq = (lane >> 4) * 8;
    const int hw = wave >> 2;            // compute half
    const int q  = wave & 3;             // quadrant
    const int mh = (q & 1) * 32, nh = (q >> 1) * 32;
    const int hs = tid >> 8;             // staging half
    const int t2 = tid & 255;
    const int sr = t2 >> 2;              // 0..63
    const int sc = (t2 & 3) * 8;         // 0,8,16,24

    __shared__ __align__(16) char smem[2 * 2 * 2 * 64 * KPAD * 2];  // 40960 B
    short* As = (short*)smem;                    // [buf][h][64][KPAD]
    short* Bs = (short*)(smem + 2 * 2 * 64 * KPAD * 2);
    float* red = (float*)smem;                   // [8][32][32] (reused after loop)

    const short* __restrict__ base = (const short*)(Hb + (size_t)b * HROWS * 2048);
    const short* __restrict__ gAm = base + (size_t)(m0 + sr) * 2048 + hs * 1024 + sc;
    const short* __restrict__ gBn = base + (size_t)(n0 + sr) * 2048 + hs * 1024 + sc;

    auto aoff = [&](int buf, int h, int r) { return ((buf * 2 + h) * 64 + r) * KPAD; };

    f32x4 acc[2][2] = {};

    // prologue: chunk 0 -> buf0 direct; chunk 1 -> regs
    *(bf16x8*)&As[aoff(0, hs, sr) + sc] = *(const bf16x8*)gAm;
    *(bf16x8*)&Bs[aoff(0, hs, sr) + sc] = *(const bf16x8*)gBn;
    bf16x8 rA = *(const bf16x8*)(gAm + 32);
    bf16x8 rB = *(const bf16x8*)(gBn + 32);
    __syncthreads();

    for (int kt = 0; kt < 32; ++kt) {
        const int cur = kt & 1;
        bf16x8 nA, nB;
        if (kt < 30) {                   // issue loads for chunk kt+2
            const int e = (kt + 2) * 32;
            nA = *(const bf16x8*)(gAm + e);
            nB = *(const bf16x8*)(gBn + e);
        }
        bf16x8 a0 = *(const bf16x8*)&As[aoff(cur, hw, mh + lrow) + kq];
        bf16x8 a1 = *(const bf16x8*)&As[aoff(cur, hw, mh + 16 + lrow) + kq];
        bf16x8 b0 = *(const bf16x8*)&Bs[aoff(cur, hw, nh + lrow) + kq];
        bf16x8 b1 = *(const bf16x8*)&Bs[aoff(cur, hw, nh + 16 + lrow) + kq];
        acc[0][0] = __builtin_amdgcn_mfma_f32_16x16x32_bf16(a0, b0, acc[0][0], 0, 0, 0);
        acc[0][1] = __builtin_amdgcn_mfma_f32_16x16x32_bf16(a0, b1, acc[0][1], 0, 0, 0);
        acc[1][0] = __builtin_amdgcn_mfma_f32_16x16x32_bf16(a1, b0, acc[1][0], 0, 0, 0);
        acc[1][1] = __builtin_amdgcn_mfma_f32_16x16x32_bf16(a1, b1, acc[1][1], 0, 0, 0);
        if (kt < 31) {                   // write chunk kt+1 (loaded an iter ago)
            *(bf16x8*)&As[aoff(cur ^ 1, hs, sr) + sc] = rA;
            *(bf16x8*)&Bs[aoff(cur ^ 1, hs, sr) + sc] = rB;
        }
        __syncthreads();                 // ONE barrier per chunk
        if (kt < 30) { rA = nA; rB = nB; }
    }

    const int ccol  = lane & 15;
    const int crow0 = (lane >> 4) * 4;
#pragma unroll
    for (int i = 0; i < 2; ++i)
#pragma unroll
        for (int j = 0; j < 2; ++j)
#pragma unroll
            for (int r = 0; r < 4; ++r)
                red[((wave * 32) + i * 16 + crow0 + r) * 32 + j * 16 + ccol] = acc[i][j][r];
    __syncthreads();

    const int q2  = tid >> 7;
    const int t7  = tid & 127;
    const int row = t7 >> 2;
    const int c8  = (t7 & 3) * 8;
    __hip_bfloat16* __restrict__ Gb = G + (size_t)b * KLD * KLD;

    // direct tile (m0, n0)
    {
        const int gm = m0 + (q2 & 1) * 32 + row;
        const int gn = n0 + (q2 >> 1) * 32 + c8;
        if (gm < KLD && gn < KLD) {
            __hip_bfloat16 o[8];
#pragma unroll
            for (int t = 0; t < 8; ++t) {
                const float v = red[((q2 * 32) + row) * 32 + c8 + t] +
                                red[(((q2 + 4) * 32) + row) * 32 + c8 + t];
                o[t] = __float2bfloat16((gm < DP && (gn + t) < DP) ? v : 0.f);
            }
            *(bf16x8*)&Gb[gm * KLD + gn] = *(const bf16x8*)o;
        }
    }
    // mirror tile (n0, m0) = transpose (skip on the diagonal)
    if (tm != tn) {
        const int gm = n0 + (q2 & 1) * 32 + row;     // n-index as G row
        const int gn = m0 + (q2 >> 1) * 32 + c8;     // m-index as G col
        if (gm < KLD && gn < KLD) {
            const int qp = ((q2 >> 1) & 1) | ((q2 & 1) << 1);  // swap quadrant bits
            __hip_bfloat16 o[8];
#pragma unroll
            for (int t = 0; t < 8; ++t) {
                const float v = red[((qp * 32) + c8 + t) * 32 + row] +
                                red[(((qp + 4) * 32) + c8 + t) * 32 + row];
                o[t] = __float2bfloat16((gm < DP && (gn + t) < DP) ? v : 0.f);
            }
            *(bf16x8*)&Gb[gm * KLD + gn] = *(const bf16x8*)o;
        }
    }
}

// ---------------------------------------------------------------------------
// C[b][m][n] = sum_k A[m][k] * B[n][k]  (K=288, ld=288), split-K x4.
// ---------------------------------------------------------------------------
__global__ __launch_bounds__(256) void mm_sk4(const __hip_bfloat16* __restrict__ A,
                                              const __hip_bfloat16* __restrict__ B,
                                              __hip_bfloat16* __restrict__ C,
                                              int strideA, int strideB) {
    const int b  = blockIdx.y;
    const int tm = blockIdx.x / 9;
    const int tn = blockIdx.x % 9;
    const int s    = threadIdx.x >> 6;
    const int lane = threadIdx.x & 63;
    const int lrow = lane & 15;
    const int koff = (lane >> 4) * 8;
    const short* __restrict__ Ab = (const short*)(A + (size_t)b * strideA);
    const short* __restrict__ Bb = (const short*)(B + (size_t)b * strideB);
    const int m0 = tm * 32, n0 = tn * 32;

    __shared__ float red[4][32][32];

    f32x4 acc[2][2] = {};
    for (int kt = s; kt < 9; kt += 4) {
        const int k0 = kt * 32;
        bf16x8 a0 = *(const bf16x8*)(Ab + (m0 + lrow)      * KLD + k0 + koff);
        bf16x8 a1 = *(const bf16x8*)(Ab + (m0 + 16 + lrow) * KLD + k0 + koff);
        bf16x8 c0 = *(const bf16x8*)(Bb + (n0 + lrow)      * KLD + k0 + koff);
        bf16x8 c1 = *(const bf16x8*)(Bb + (n0 + 16 + lrow) * KLD + k0 + koff);
        acc[0][0] = __builtin_amdgcn_mfma_f32_16x16x32_bf16(a0, c0, acc[0][0], 0, 0, 0);
        acc[0][1] = __builtin_amdgcn_mfma_f32_16x16x32_bf16(a0, c1, acc[0][1], 0, 0, 0);
        acc[1][0] = __builtin_amdgcn_mfma_f32_16x16x32_bf16(a1, c0, acc[1][0], 0, 0, 0);
        acc[1][1] = __builtin_amdgcn_mfma_f32_16x16x32_bf16(a1, c1, acc[1][1], 0, 0, 0);
    }

    const int ccol  = lane & 15;
    const int crow0 = (lane >> 4) * 4;
#pragma unroll
    for (int i = 0; i < 2; ++i)
#pragma unroll
        for (int j = 0; j < 2; ++j)
#pragma unroll
            for (int r = 0; r < 4; ++r)
                red[s][i * 16 + crow0 + r][j * 16 + ccol] = acc[i][j][r];
    __syncthreads();

    const int row = threadIdx.x >> 3;
    const int c4  = (threadIdx.x & 7) * 4;
    float4 v0 = *(const float4*)&red[0][row][c4];
    float4 v1 = *(const float4*)&red[1][row][c4];
    float4 v2 = *(const float4*)&red[2][row][c4];
    float4 v3 = *(const float4*)&red[3][row][c4];
    float sum[4] = {v0.x + v1.x + v2.x + v3.x,
                    v0.y + v1.y + v2.y + v3.y,
                    v0.z + v1.z + v2.z + v3.z,
                    v0.w + v1.w + v2.w + v3.w};
    const int gm = m0 + row;
    const int gn = n0 + c4;
    __hip_bfloat16 o[4];
#pragma unroll
    for (int t = 0; t < 4; ++t) {
        const float v = (gm < DP && (gn + t) < DP) ? sum[t] : 0.f;
        o[t] = __float2bfloat16(v);
    }
    __hip_bfloat16* __restrict__ Cb = C + (size_t)b * KLD * KLD;
    *(bf16x4*)&Cb[gm * KLD + gn] = *(const bf16x4*)o;
}

// ---------------------------------------------------------------------------
// out[b][d][t] = H[b][d][t] + (1/n) * sum_e Kb[d][e] * Hbt[t][e]
//
// v8 = v7 with occupancy raised 4 -> 6 blocks/CU: ATKP=34 pitch (26112 B LDS,
// 17-dword row stride -> frag reads conflict-free, staging writes <=2-way =
// free) + __launch_bounds__(256,6). Grid 5.3 blocks/CU now fully resident
// in ~one scheduling wave (was 1.33 waves at 4/CU residency).
// ---------------------------------------------------------------------------
__global__ __launch_bounds__(256, 6) void attn_v8(const __hip_bfloat16* __restrict__ Kb,
                                                  const __hip_bfloat16* __restrict__ Hbt,
                                                  const float* __restrict__ H,
                                                  float* __restrict__ Out) {
    // XCD swizzle: 1360 blocks, 170 per XCD = 2 batches (85 = 17t x 5d each)
    const int id      = blockIdx.x;
    const int logical = (id & 7) * 170 + (id >> 3);
    const int b   = logical / 85;
    const int rem = logical % 85;
    const int t0  = (rem / 5) * 128;
    const int d0  = (rem % 5) * 64;

    const int tid = threadIdx.x;
    const int wave = tid >> 6, lane = tid & 63;
    const int lrow = lane & 15, kq = (lane >> 4) * 8;
    const int dh = (wave & 1) * 32;      // wave's d-half
    const int th = (wave >> 1) * 64;     // wave's t-half
    const int sr = tid >> 2;             // 0..63
    const int sc = (tid & 3) * 8;        // 0,8,16,24
    const int ccol  = lane & 15;
    const int crow0 = (lane >> 4) * 4;

    __shared__ __align__(16) char smem[2 * 192 * ATKP * 2];  // 26112 B
    // buffer i: A rows [0,64), B rows [64,192) at base i*192*ATKP (shorts)
    short* bufs = (short*)smem;
    float* Ped  = (float*)smem;          // [32][132] epilogue staging (16896 B)

    const short* __restrict__ Ka = (const short*)(Kb  + (size_t)b * KLD * KLD);
    const short* __restrict__ Ta = (const short*)(Hbt + (size_t)b * TROWS * TPITCH);

    int rA = d0 + sr; if (rA > KLD - 1) rA = KLD - 1;   // Kb rows 257..287 are zeros
    const short* __restrict__ gA  = Ka + (size_t)rA * KLD + sc;
    const short* __restrict__ gB0 = Ta + (size_t)(t0 + sr) * TPITCH + sc;
    const short* __restrict__ gB1 = Ta + (size_t)(t0 + 64 + sr) * TPITCH + sc;

    auto Aoff = [&](int bi, int r) { return (bi * 192 + r) * ATKP; };
    auto Boff = [&](int bi, int r) { return (bi * 192 + 64 + r) * ATKP; };

    f32x4 acc[2][4] = {};

    // prologue: chunk 0 -> buf0 (direct), chunk 1 -> regs R
    {
        bf16x8 a = *(const bf16x8*)gA;
        bf16x8 x = *(const bf16x8*)gB0;
        bf16x8 y = *(const bf16x8*)gB1;
        *(bf16x8*)&bufs[Aoff(0, sr) + sc]      = a;
        *(bf16x8*)&bufs[Boff(0, sr) + sc]      = x;
        *(bf16x8*)&bufs[Boff(0, 64 + sr) + sc] = y;
    }
    bf16x8 rA1 = *(const bf16x8*)(gA  + 32);
    bf16x8 rB0 = *(const bf16x8*)(gB0 + 32);
    bf16x8 rB1 = *(const bf16x8*)(gB1 + 32);
    __syncthreads();

#pragma unroll
    for (int kt = 0; kt < 8; ++kt) {
        const int cur = kt & 1;
        // issue loads for chunk kt+2 (consumed at iteration kt+1's ds_write)
        bf16x8 nA, nB0, nB1;
        if (kt < 6) {
            const int e = (kt + 2) * 32;
            nA  = *(const bf16x8*)(gA  + e);
            nB0 = *(const bf16x8*)(gB0 + e);
            nB1 = *(const bf16x8*)(gB1 + e);
        }
        // compute on buf[cur]
        bf16x8 af0 = *(const bf16x8*)&bufs[Aoff(cur, dh + lrow) + kq];
        bf16x8 af1 = *(const bf16x8*)&bufs[Aoff(cur, dh + 16 + lrow) + kq];
        bf16x8 bfr[4];
#pragma unroll
        for (int j = 0; j < 4; ++j)
            bfr[j] = *(const bf16x8*)&bufs[Boff(cur, th + j * 16 + lrow) + kq];
#pragma unroll
        for (int j = 0; j < 4; ++j) {
            acc[0][j] = __builtin_amdgcn_mfma_f32_16x16x32_bf16(af0, bfr[j], acc[0][j], 0, 0, 0);
            acc[1][j] = __builtin_amdgcn_mfma_f32_16x16x32_bf16(af1, bfr[j], acc[1][j], 0, 0, 0);
        }
        // write chunk kt+1 (loaded a full iteration ago) into the other buffer
        if (kt < 7) {
            *(bf16x8*)&bufs[Aoff(cur ^ 1, sr) + sc]      = rA1;
            *(bf16x8*)&bufs[Boff(cur ^ 1, sr) + sc]      = rB0;
            *(bf16x8*)&bufs[Boff(cur ^ 1, 64 + sr) + sc] = rB1;
        }
        __syncthreads();                  // ONE barrier per chunk
        if (kt < 6) { rA1 = nA; rB0 = nB0; rB1 = nB1; }
    }

    // rank-1 update for e = 256 (replaces chunk 8; Kb/Hbt cols >256 are zero)
    {
        float bv[4];
#pragma unroll
        for (int j = 0; j < 4; ++j) {
            const int tt = t0 + th + j * 16 + ccol;
            bv[j] = __bfloat162float(*(const __hip_bfloat16*)&Ta[(size_t)tt * TPITCH + 256]);
        }
#pragma unroll
        for (int i = 0; i < 2; ++i)
#pragma unroll
            for (int r = 0; r < 4; ++r) {
                int rr = d0 + dh + i * 16 + crow0 + r;
                if (rr > KLD - 1) rr = KLD - 1;           // zero rows
                const float av = __bfloat162float(*(const __hip_bfloat16*)&Ka[(size_t)rr * KLD + 256]);
#pragma unroll
                for (int j = 0; j < 4; ++j)
                    acc[i][j][r] += av * bv[j];
            }
    }

    // ---------------- epilogue ----------------
    const float* __restrict__ Hs = H + (size_t)b * DP * NP;
    float* __restrict__ Ob = Out + (size_t)b * DP * NP;
    const float inv_n = 1.0f / (float)NSEQ;
    const int prow = tid >> 5;           // 0..7
    const int pcol = (tid & 31) * 4;     // 0..124

    // preload the entire 64x128 H tile: 32 regs/thread, one MLP burst
    float hreg[4][2][4];
#pragma unroll
    for (int c = 0; c < 4; ++c)
#pragma unroll
        for (int p = 0; p < 2; ++p) {
            const int gd = d0 + c * 16 + p * 8 + prow;
            if (gd < DP) {
                const size_t base = (size_t)gd * NP + t0;
#pragma unroll
                for (int cc = 0; cc < 4; ++cc) {
                    const int gt = t0 + pcol + cc;
                    if (gt < NP) hreg[c][p][cc] = Hs[base + pcol + cc];
                }
            }
        }

    // 2 phases of 32 d-rows
#pragma unroll
    for (int c2 = 0; c2 < 2; ++c2) {
        if ((wave & 1) == c2) {          // this wave's d-half == phase rows
#pragma unroll
            for (int i = 0; i < 2; ++i)
#pragma unroll
                for (int j = 0; j < 4; ++j)
#pragma unroll
                    for (int r = 0; r < 4; ++r)
                        Ped[(i * 16 + crow0 + r) * 132 + th + j * 16 + ccol] = acc[i][j][r];
        }
        __syncthreads();
#pragma unroll
        for (int c = 2 * c2; c < 2 * c2 + 2; ++c)
#pragma unroll
            for (int p = 0; p < 2; ++p) {
                const int rloc = (c & 1) * 16 + p * 8 + prow;   // 0..31
                const int gd = d0 + c * 16 + p * 8 + prow;
                if (gd < DP) {
                    const float4 pv = *(const float4*)&Ped[rloc * 132 + pcol];
                    const size_t base = (size_t)gd * NP + t0;
                    const float pva[4] = {pv.x, pv.y, pv.z, pv.w};
#pragma unroll
                    for (int cc = 0; cc < 4; ++cc) {
                        const int gt = t0 + pcol + cc;
                        if (gt < NP) Ob[base + pcol + cc] = hreg[c][p][cc] + inv_n * pva[cc];
                    }
                }
            }
        if (c2 == 0) __syncthreads();    // Ped reused by phase 1
    }
}

extern "C" void kernel_launch(void* const* d_in, const int* in_sizes, int n_in,
                              void* d_out, int out_size, void* d_ws, size_t ws_size,
                              hipStream_t stream) {
    const float* H = (const float*)d_in[0];
    const float* P = (const float*)d_in[1];
    const float* Q = (const float*)d_in[2];
    float* out = (float*)d_out;

    __hip_bfloat16* Hb  = (__hip_bfloat16*)d_ws;                   // 16*320*2048
    __hip_bfloat16* Hbt = Hb  + (size_t)NB * HROWS * 2048;         // 16*2176*320
    __hip_bfloat16* G   = Hbt + (size_t)NB * TROWS * TPITCH;       // 16*288*288
    __hip_bfloat16* Pb  = G   + (size_t)NB * KLD * KLD;            // 288*288
    __hip_bfloat16* Qt  = Pb  + (size_t)KLD * KLD;                 // 288*288
    // W and Kb alias Hb's region (Hb is dead after gram_staged)
    __hip_bfloat16* W   = Hb;
    __hip_bfloat16* Kb  = Hb + (size_t)NB * KLD * KLD;

    // fused conversions: H (z<16) + P/Q (z==16) in one launch
    conv_all<<<dim3(34, 5, NB + 1), 256, 0, stream>>>(H, P, Q, Hb, Hbt, Pb, Qt);
    // G[b] = H-hat @ H-hat^T  (upper-triangle tiles + mirrored writes, pipelined)
    gram_staged<<<dim3(15, NB), 512, 0, stream>>>(Hb, G);
    // W[b] = P @ G[b]   (B-frags = G rows, valid by symmetry of G)
    mm_sk4<<<dim3(81, NB), 256, 0, stream>>>(Pb, G, W, 0, KLD * KLD);
    // Kb[b] = W[b] @ Q  (B-frags = Qt rows)
    mm_sk4<<<dim3(81, NB), 256, 0, stream>>>(W, Qt, Kb, KLD * KLD, 0);
    // out = H + (Kb @ H) / n  (single launch, XCD-swizzled 1-D grid)
    attn_v8<<<dim3(17 * 5 * NB), 256, 0, stream>>>(Kb, Hbt, H, out);
}

// Round 9
// 161.307 us; speedup vs baseline: 1.2321x; 1.2321x over previous
//
#include <hip/hip_runtime.h>
#include <hip/hip_bf16.h>

#define DP     257
#define NP     2049
#define NSEQ   2048
#define NB     16
#define KLD    288         // pitch for small matrices (shorts)
#define HROWS  320         // padded rows for Hb
#define TPITCH 320         // Hbt pitch in shorts: 640 B = 5 full 128B lines
#define TROWS  2176        // padded t rows for Hbt (17*128)
#define KPAD   40          // LDS row pitch (shorts)

typedef __attribute__((ext_vector_type(8))) short bf16x8;
typedef __attribute__((ext_vector_type(4))) short bf16x4;
typedef __attribute__((ext_vector_type(4))) float f32x4;

// ---------------------------------------------------------------------------
// Fused conversion kernel.
//  z < NB : H -> Hb (row-major bf16, masked H-hat) and Hbt (transposed)
//  z == NB: bx<5 -> Pb[m][k]=P (zero-padded 288x288); bx in 5..9 -> Qt[n][k]=Q[k][n]
// ---------------------------------------------------------------------------
__global__ __launch_bounds__(256) void conv_all(const float* __restrict__ H,
                                                const float* __restrict__ P,
                                                const float* __restrict__ Q,
                                                __hip_bfloat16* __restrict__ Hb,
                                                __hip_bfloat16* __restrict__ Hbt,
                                                __hip_bfloat16* __restrict__ Pb,
                                                __hip_bfloat16* __restrict__ Qt) {
    const int z  = blockIdx.z;
    const int tl = threadIdx.x & 63;
    const int er = threadIdx.x >> 6;
    __shared__ float tile[64][65];

    if (z < NB) {
        const int b  = z;
        const int t0 = blockIdx.x * 64;
        const int e0 = blockIdx.y * 64;
        const float* __restrict__ Hs = H + (size_t)b * DP * NP;
        __hip_bfloat16* __restrict__ Hbb  = Hb  + (size_t)b * HROWS * 2048;
        __hip_bfloat16* __restrict__ Hbtb = Hbt + (size_t)b * TROWS * TPITCH;

#pragma unroll
        for (int r = 0; r < 16; ++r) {
            const int el = er + r * 4;        // 0..63
            const int ge = e0 + el;
            const int gt = t0 + tl;
            float v = 0.f;
            if (ge < DP && gt < NP) v = Hs[(size_t)ge * NP + gt];
            tile[el][tl] = v;
            if (ge < HROWS && gt < 2048) Hbb[(size_t)ge * 2048 + gt] = __float2bfloat16(v);
        }
        __syncthreads();
#pragma unroll
        for (int r = 0; r < 16; ++r) {
            const int ttl = er + r * 4;       // t-local
            const int gt = t0 + ttl;
            const int ge = e0 + tl;           // e-local = lane -> contiguous writes
            if (gt < TROWS && ge < TPITCH) {
                const float v = (ge < KLD) ? tile[tl][ttl] : 0.f;
                Hbtb[(size_t)gt * TPITCH + ge] = __float2bfloat16(v);
            }
        }
        return;
    }

    // z == NB: P/Q conversion (50 blocks ride along)
    const int bx = blockIdx.x;
    if (bx >= 10) return;
    const int r0 = blockIdx.y * 64;
    if (bx < 5) {
        const int c0 = bx * 64;
#pragma unroll
        for (int r = 0; r < 16; ++r) {
            const int m = r0 + er + r * 4;
            const int k = c0 + tl;
            float v = (m < DP && k < DP) ? P[m * DP + k] : 0.f;
            if (m < KLD && k < KLD) Pb[m * KLD + k] = __float2bfloat16(v);
        }
    } else {
        const int c0 = (bx - 5) * 64;
#pragma unroll
        for (int r = 0; r < 16; ++r) {
            const int k = r0 + er + r * 4;
            const int n = c0 + tl;
            float v = (k < DP && n < DP) ? Q[k * DP + n] : 0.f;
            tile[k - r0][n - c0] = v;
        }
        __syncthreads();
#pragma unroll
        for (int r = 0; r < 16; ++r) {
            const int k = r0 + tl;
            const int n = c0 + er + r * 4;
            if (n < KLD && k < KLD) Qt[n * KLD + k] = __float2bfloat16(tile[tl][n - c0]);
        }
    }
}

// ---------------------------------------------------------------------------
// G[b] = Hb[b] @ Hb[b]^T  -- upper-triangle tiles (15 of 25), mirror written
// transposed. 240 blocks, 512 threads, split-K x2 in-block.
// Pipelined: 2-deep register prefetch, ds_write of chunk kt+1 after the
// MFMAs, ONE barrier per chunk, no same-chunk vmcnt stall. (kept from R8 —
// R8's non-attn time improved ~10 us with this in place)
// ---------------------------------------------------------------------------
__global__ __launch_bounds__(512, 4) void gram_staged(const __hip_bfloat16* __restrict__ Hb,
                                                      __hip_bfloat16* __restrict__ G) {
    const int b  = blockIdx.y;
    // enumerate upper-triangle tiles: (0,0)..(0,4),(1,1)..(4,4)
    int idx = blockIdx.x, tm = 0, w = 5;
    while (idx >= w) { idx -= w; ++tm; --w; }
    const int tn = tm + idx;
    const int m0 = tm * 64, n0 = tn * 64;
    const int tid = threadIdx.x;
    const int wave = tid >> 6, lane = tid & 63;
    const int lrow = lane & 15, kq = (lane >> 4) * 8;
    const int hw = wave >> 2;            // compute half
    const int q  = wave & 3;             // quadrant
    const int mh = (q & 1) * 32, nh = (q >> 1) * 32;
    const int hs = tid >> 8;             // staging half
    const int t2 = tid & 255;
    const int sr = t2 >> 2;              // 0..63
    const int sc = (t2 & 3) * 8;         // 0,8,16,24

    __shared__ __align__(16) char smem[2 * 2 * 2 * 64 * KPAD * 2];  // 40960 B
    short* As = (short*)smem;                    // [buf][h][64][KPAD]
    short* Bs = (short*)(smem + 2 * 2 * 64 * KPAD * 2);
    float* red = (float*)smem;                   // [8][32][32] (reused after loop)

    const short* __restrict__ base = (const short*)(Hb + (size_t)b * HROWS * 2048);
    const short* __restrict__ gAm = base + (size_t)(m0 + sr) * 2048 + hs * 1024 + sc;
    const short* __restrict__ gBn = base + (size_t)(n0 + sr) * 2048 + hs * 1024 + sc;

    auto aoff = [&](int buf, int h, int r) { return ((buf * 2 + h) * 64 + r) * KPAD; };

    f32x4 acc[2][2] = {};

    // prologue: chunk 0 -> buf0 direct; chunk 1 -> regs
    *(bf16x8*)&As[aoff(0, hs, sr) + sc] = *(const bf16x8*)gAm;
    *(bf16x8*)&Bs[aoff(0, hs, sr) + sc] = *(const bf16x8*)gBn;
    bf16x8 rA = *(const bf16x8*)(gAm + 32);
    bf16x8 rB = *(const bf16x8*)(gBn + 32);
    __syncthreads();

    for (int kt = 0; kt < 32; ++kt) {
        const int cur = kt & 1;
        bf16x8 nA, nB;
        if (kt < 30) {                   // issue loads for chunk kt+2
            const int e = (kt + 2) * 32;
            nA = *(const bf16x8*)(gAm + e);
            nB = *(const bf16x8*)(gBn + e);
        }
        bf16x8 a0 = *(const bf16x8*)&As[aoff(cur, hw, mh + lrow) + kq];
        bf16x8 a1 = *(const bf16x8*)&As[aoff(cur, hw, mh + 16 + lrow) + kq];
        bf16x8 b0 = *(const bf16x8*)&Bs[aoff(cur, hw, nh + lrow) + kq];
        bf16x8 b1 = *(const bf16x8*)&Bs[aoff(cur, hw, nh + 16 + lrow) + kq];
        acc[0][0] = __builtin_amdgcn_mfma_f32_16x16x32_bf16(a0, b0, acc[0][0], 0, 0, 0);
        acc[0][1] = __builtin_amdgcn_mfma_f32_16x16x32_bf16(a0, b1, acc[0][1], 0, 0, 0);
        acc[1][0] = __builtin_amdgcn_mfma_f32_16x16x32_bf16(a1, b0, acc[1][0], 0, 0, 0);
        acc[1][1] = __builtin_amdgcn_mfma_f32_16x16x32_bf16(a1, b1, acc[1][1], 0, 0, 0);
        if (kt < 31) {                   // write chunk kt+1 (loaded an iter ago)
            *(bf16x8*)&As[aoff(cur ^ 1, hs, sr) + sc] = rA;
            *(bf16x8*)&Bs[aoff(cur ^ 1, hs, sr) + sc] = rB;
        }
        __syncthreads();                 // ONE barrier per chunk
        if (kt < 30) { rA = nA; rB = nB; }
    }

    const int ccol  = lane & 15;
    const int crow0 = (lane >> 4) * 4;
#pragma unroll
    for (int i = 0; i < 2; ++i)
#pragma unroll
        for (int j = 0; j < 2; ++j)
#pragma unroll
            for (int r = 0; r < 4; ++r)
                red[((wave * 32) + i * 16 + crow0 + r) * 32 + j * 16 + ccol] = acc[i][j][r];
    __syncthreads();

    const int q2  = tid >> 7;
    const int t7  = tid & 127;
    const int row = t7 >> 2;
    const int c8  = (t7 & 3) * 8;
    __hip_bfloat16* __restrict__ Gb = G + (size_t)b * KLD * KLD;

    // direct tile (m0, n0)
    {
        const int gm = m0 + (q2 & 1) * 32 + row;
        const int gn = n0 + (q2 >> 1) * 32 + c8;
        if (gm < KLD && gn < KLD) {
            __hip_bfloat16 o[8];
#pragma unroll
            for (int t = 0; t < 8; ++t) {
                const float v = red[((q2 * 32) + row) * 32 + c8 + t] +
                                red[(((q2 + 4) * 32) + row) * 32 + c8 + t];
                o[t] = __float2bfloat16((gm < DP && (gn + t) < DP) ? v : 0.f);
            }
            *(bf16x8*)&Gb[gm * KLD + gn] = *(const bf16x8*)o;
        }
    }
    // mirror tile (n0, m0) = transpose (skip on the diagonal)
    if (tm != tn) {
        const int gm = n0 + (q2 & 1) * 32 + row;     // n-index as G row
        const int gn = m0 + (q2 >> 1) * 32 + c8;     // m-index as G col
        if (gm < KLD && gn < KLD) {
            const int qp = ((q2 >> 1) & 1) | ((q2 & 1) << 1);  // swap quadrant bits
            __hip_bfloat16 o[8];
#pragma unroll
            for (int t = 0; t < 8; ++t) {
                const float v = red[((qp * 32) + c8 + t) * 32 + row] +
                                red[(((qp + 4) * 32) + c8 + t) * 32 + row];
                o[t] = __float2bfloat16((gm < DP && (gn + t) < DP) ? v : 0.f);
            }
            *(bf16x8*)&Gb[gm * KLD + gn] = *(const bf16x8*)o;
        }
    }
}

// ---------------------------------------------------------------------------
// C[b][m][n] = sum_k A[m][k] * B[n][k]  (K=288, ld=288), split-K x4.
// ---------------------------------------------------------------------------
__global__ __launch_bounds__(256) void mm_sk4(const __hip_bfloat16* __restrict__ A,
                                              const __hip_bfloat16* __restrict__ B,
                                              __hip_bfloat16* __restrict__ C,
                                              int strideA, int strideB) {
    const int b  = blockIdx.y;
    const int tm = blockIdx.x / 9;
    const int tn = blockIdx.x % 9;
    const int s    = threadIdx.x >> 6;
    const int lane = threadIdx.x & 63;
    const int lrow = lane & 15;
    const int koff = (lane >> 4) * 8;
    const short* __restrict__ Ab = (const short*)(A + (size_t)b * strideA);
    const short* __restrict__ Bb = (const short*)(B + (size_t)b * strideB);
    const int m0 = tm * 32, n0 = tn * 32;

    __shared__ float red[4][32][32];

    f32x4 acc[2][2] = {};
    for (int kt = s; kt < 9; kt += 4) {
        const int k0 = kt * 32;
        bf16x8 a0 = *(const bf16x8*)(Ab + (m0 + lrow)      * KLD + k0 + koff);
        bf16x8 a1 = *(const bf16x8*)(Ab + (m0 + 16 + lrow) * KLD + k0 + koff);
        bf16x8 c0 = *(const bf16x8*)(Bb + (n0 + lrow)      * KLD + k0 + koff);
        bf16x8 c1 = *(const bf16x8*)(Bb + (n0 + 16 + lrow) * KLD + k0 + koff);
        acc[0][0] = __builtin_amdgcn_mfma_f32_16x16x32_bf16(a0, c0, acc[0][0], 0, 0, 0);
        acc[0][1] = __builtin_amdgcn_mfma_f32_16x16x32_bf16(a0, c1, acc[0][1], 0, 0, 0);
        acc[1][0] = __builtin_amdgcn_mfma_f32_16x16x32_bf16(a1, c0, acc[1][0], 0, 0, 0);
        acc[1][1] = __builtin_amdgcn_mfma_f32_16x16x32_bf16(a1, c1, acc[1][1], 0, 0, 0);
    }

    const int ccol  = lane & 15;
    const int crow0 = (lane >> 4) * 4;
#pragma unroll
    for (int i = 0; i < 2; ++i)
#pragma unroll
        for (int j = 0; j < 2; ++j)
#pragma unroll
            for (int r = 0; r < 4; ++r)
                red[s][i * 16 + crow0 + r][j * 16 + ccol] = acc[i][j][r];
    __syncthreads();

    const int row = threadIdx.x >> 3;
    const int c4  = (threadIdx.x & 7) * 4;
    float4 v0 = *(const float4*)&red[0][row][c4];
    float4 v1 = *(const float4*)&red[1][row][c4];
    float4 v2 = *(const float4*)&red[2][row][c4];
    float4 v3 = *(const float4*)&red[3][row][c4];
    float sum[4] = {v0.x + v1.x + v2.x + v3.x,
                    v0.y + v1.y + v2.y + v3.y,
                    v0.z + v1.z + v2.z + v3.z,
                    v0.w + v1.w + v2.w + v3.w};
    const int gm = m0 + row;
    const int gn = n0 + c4;
    __hip_bfloat16 o[4];
#pragma unroll
    for (int t = 0; t < 4; ++t) {
        const float v = (gm < DP && (gn + t) < DP) ? sum[t] : 0.f;
        o[t] = __float2bfloat16(v);
    }
    __hip_bfloat16* __restrict__ Cb = C + (size_t)b * KLD * KLD;
    *(bf16x4*)&Cb[gm * KLD + gn] = *(const bf16x4*)o;
}

// ---------------------------------------------------------------------------
// out[b][d][t] = H[b][d][t] + (1/n) * sum_e Kb[d][e] * Hbt[t][e]
//
// attn_v7 VERBATIM (proven as part of the 166.6 us build): KPAD=40 pitch,
// __launch_bounds__(256,4), double-buffered LDS, 1 barrier/chunk, 2-deep
// register prefetch, 8 chunks + rank-1 e=256 update, XCD-swizzled grid.
// (R8's ATKP=34 + (256,6) experiment collapsed HBM BW to 1.2 TB/s — reverted.)
// ---------------------------------------------------------------------------
__global__ __launch_bounds__(256, 4) void attn_v7(const __hip_bfloat16* __restrict__ Kb,
                                                  const __hip_bfloat16* __restrict__ Hbt,
                                                  const float* __restrict__ H,
                                                  float* __restrict__ Out) {
    // XCD swizzle: 1360 blocks, 170 per XCD = 2 batches (85 = 17t x 5d each)
    const int id      = blockIdx.x;
    const int logical = (id & 7) * 170 + (id >> 3);
    const int b   = logical / 85;
    const int rem = logical % 85;
    const int t0  = (rem / 5) * 128;
    const int d0  = (rem % 5) * 64;

    const int tid = threadIdx.x;
    const int wave = tid >> 6, lane = tid & 63;
    const int lrow = lane & 15, kq = (lane >> 4) * 8;
    const int dh = (wave & 1) * 32;      // wave's d-half
    const int th = (wave >> 1) * 64;     // wave's t-half
    const int sr = tid >> 2;             // 0..63
    const int sc = (tid & 3) * 8;        // 0,8,16,24
    const int ccol  = lane & 15;
    const int crow0 = (lane >> 4) * 4;

    __shared__ __align__(16) char smem[2 * (64 + 128) * KPAD * 2];  // 30720 B
    // buffer i: A rows [0,64), B rows [64,192) at base i*192*KPAD (shorts)
    short* bufs = (short*)smem;
    float* Ped  = (float*)smem;          // [32][132] epilogue staging (16896 B)

    const short* __restrict__ Ka = (const short*)(Kb  + (size_t)b * KLD * KLD);
    const short* __restrict__ Ta = (const short*)(Hbt + (size_t)b * TROWS * TPITCH);

    int rA = d0 + sr; if (rA > KLD - 1) rA = KLD - 1;   // Kb rows 257..287 are zeros
    const short* __restrict__ gA  = Ka + (size_t)rA * KLD + sc;
    const short* __restrict__ gB0 = Ta + (size_t)(t0 + sr) * TPITCH + sc;
    const short* __restrict__ gB1 = Ta + (size_t)(t0 + 64 + sr) * TPITCH + sc;

    auto Aoff = [&](int bi, int r) { return (bi * 192 + r) * KPAD; };
    auto Boff = [&](int bi, int r) { return (bi * 192 + 64 + r) * KPAD; };

    f32x4 acc[2][4] = {};

    // prologue: chunk 0 -> buf0 (direct), chunk 1 -> regs R
    {
        bf16x8 a = *(const bf16x8*)gA;
        bf16x8 x = *(const bf16x8*)gB0;
        bf16x8 y = *(const bf16x8*)gB1;
        *(bf16x8*)&bufs[Aoff(0, sr) + sc]      = a;
        *(bf16x8*)&bufs[Boff(0, sr) + sc]      = x;
        *(bf16x8*)&bufs[Boff(0, 64 + sr) + sc] = y;
    }
    bf16x8 rA1 = *(const bf16x8*)(gA  + 32);
    bf16x8 rB0 = *(const bf16x8*)(gB0 + 32);
    bf16x8 rB1 = *(const bf16x8*)(gB1 + 32);
    __syncthreads();

#pragma unroll
    for (int kt = 0; kt < 8; ++kt) {
        const int cur = kt & 1;
        // issue loads for chunk kt+2 (consumed at iteration kt+1's ds_write)
        bf16x8 nA, nB0, nB1;
        if (kt < 6) {
            const int e = (kt + 2) * 32;
            nA  = *(const bf16x8*)(gA  + e);
            nB0 = *(const bf16x8*)(gB0 + e);
            nB1 = *(const bf16x8*)(gB1 + e);
        }
        // compute on buf[cur]
        bf16x8 af0 = *(const bf16x8*)&bufs[Aoff(cur, dh + lrow) + kq];
        bf16x8 af1 = *(const bf16x8*)&bufs[Aoff(cur, dh + 16 + lrow) + kq];
        bf16x8 bfr[4];
#pragma unroll
        for (int j = 0; j < 4; ++j)
            bfr[j] = *(const bf16x8*)&bufs[Boff(cur, th + j * 16 + lrow) + kq];
#pragma unroll
        for (int j = 0; j < 4; ++j) {
            acc[0][j] = __builtin_amdgcn_mfma_f32_16x16x32_bf16(af0, bfr[j], acc[0][j], 0, 0, 0);
            acc[1][j] = __builtin_amdgcn_mfma_f32_16x16x32_bf16(af1, bfr[j], acc[1][j], 0, 0, 0);
        }
        // write chunk kt+1 (loaded a full iteration ago) into the other buffer
        if (kt < 7) {
            *(bf16x8*)&bufs[Aoff(cur ^ 1, sr) + sc]      = rA1;
            *(bf16x8*)&bufs[Boff(cur ^ 1, sr) + sc]      = rB0;
            *(bf16x8*)&bufs[Boff(cur ^ 1, 64 + sr) + sc] = rB1;
        }
        __syncthreads();                  // ONE barrier per chunk
        if (kt < 6) { rA1 = nA; rB0 = nB0; rB1 = nB1; }
    }

    // rank-1 update for e = 256 (replaces chunk 8; Kb/Hbt cols >256 are zero)
    {
        float bv[4];
#pragma unroll
        for (int j = 0; j < 4; ++j) {
            const int tt = t0 + th + j * 16 + ccol;
            bv[j] = __bfloat162float(*(const __hip_bfloat16*)&Ta[(size_t)tt * TPITCH + 256]);
        }
#pragma unroll
        for (int i = 0; i < 2; ++i)
#pragma unroll
            for (int r = 0; r < 4; ++r) {
                int rr = d0 + dh + i * 16 + crow0 + r;
                if (rr > KLD - 1) rr = KLD - 1;           // zero rows
                const float av = __bfloat162float(*(const __hip_bfloat16*)&Ka[(size_t)rr * KLD + 256]);
#pragma unroll
                for (int j = 0; j < 4; ++j)
                    acc[i][j][r] += av * bv[j];
            }
    }

    // ---------------- epilogue ----------------
    const float* __restrict__ Hs = H + (size_t)b * DP * NP;
    float* __restrict__ Ob = Out + (size_t)b * DP * NP;
    const float inv_n = 1.0f / (float)NSEQ;
    const int prow = tid >> 5;           // 0..7
    const int pcol = (tid & 31) * 4;     // 0..124

    // preload the entire 64x128 H tile: 32 regs/thread, one MLP burst
    float hreg[4][2][4];
#pragma unroll
    for (int c = 0; c < 4; ++c)
#pragma unroll
        for (int p = 0; p < 2; ++p) {
            const int gd = d0 + c * 16 + p * 8 + prow;
            if (gd < DP) {
                const size_t base = (size_t)gd * NP + t0;
#pragma unroll
                for (int cc = 0; cc < 4; ++cc) {
                    const int gt = t0 + pcol + cc;
                    if (gt < NP) hreg[c][p][cc] = Hs[base + pcol + cc];
                }
            }
        }

    // 2 phases of 32 d-rows
#pragma unroll
    for (int c2 = 0; c2 < 2; ++c2) {
        if ((wave & 1) == c2) {          // this wave's d-half == phase rows
#pragma unroll
            for (int i = 0; i < 2; ++i)
#pragma unroll
                for (int j = 0; j < 4; ++j)
#pragma unroll
                    for (int r = 0; r < 4; ++r)
                        Ped[(i * 16 + crow0 + r) * 132 + th + j * 16 + ccol] = acc[i][j][r];
        }
        __syncthreads();
#pragma unroll
        for (int c = 2 * c2; c < 2 * c2 + 2; ++c)
#pragma unroll
            for (int p = 0; p < 2; ++p) {
                const int rloc = (c & 1) * 16 + p * 8 + prow;   // 0..31
                const int gd = d0 + c * 16 + p * 8 + prow;
                if (gd < DP) {
                    const float4 pv = *(const float4*)&Ped[rloc * 132 + pcol];
                    const size_t base = (size_t)gd * NP + t0;
                    const float pva[4] = {pv.x, pv.y, pv.z, pv.w};
#pragma unroll
                    for (int cc = 0; cc < 4; ++cc) {
                        const int gt = t0 + pcol + cc;
                        if (gt < NP) Ob[base + pcol + cc] = hreg[c][p][cc] + inv_n * pva[cc];
                    }
                }
            }
        if (c2 == 0) __syncthreads();    // Ped reused by phase 1
    }
}

extern "C" void kernel_launch(void* const* d_in, const int* in_sizes, int n_in,
                              void* d_out, int out_size, void* d_ws, size_t ws_size,
                              hipStream_t stream) {
    const float* H = (const float*)d_in[0];
    const float* P = (const float*)d_in[1];
    const float* Q = (const float*)d_in[2];
    float* out = (float*)d_out;

    __hip_bfloat16* Hb  = (__hip_bfloat16*)d_ws;                   // 16*320*2048
    __hip_bfloat16* Hbt = Hb  + (size_t)NB * HROWS * 2048;         // 16*2176*320
    __hip_bfloat16* G   = Hbt + (size_t)NB * TROWS * TPITCH;       // 16*288*288
    __hip_bfloat16* Pb  = G   + (size_t)NB * KLD * KLD;            // 288*288
    __hip_bfloat16* Qt  = Pb  + (size_t)KLD * KLD;                 // 288*288
    // W and Kb alias Hb's region (Hb is dead after gram_staged)
    __hip_bfloat16* W   = Hb;
    __hip_bfloat16* Kb  = Hb + (size_t)NB * KLD * KLD;

    // fused conversions: H (z<16) + P/Q (z==16) in one launch
    conv_all<<<dim3(34, 5, NB + 1), 256, 0, stream>>>(H, P, Q, Hb, Hbt, Pb, Qt);
    // G[b] = H-hat @ H-hat^T  (upper-triangle tiles + mirrored writes, pipelined)
    gram_staged<<<dim3(15, NB), 512, 0, stream>>>(Hb, G);
    // W[b] = P @ G[b]   (B-frags = G rows, valid by symmetry of G)
    mm_sk4<<<dim3(81, NB), 256, 0, stream>>>(Pb, G, W, 0, KLD * KLD);
    // Kb[b] = W[b] @ Q  (B-frags = Qt rows)
    mm_sk4<<<dim3(81, NB), 256, 0, stream>>>(W, Qt, Kb, KLD * KLD, 0);
    // out = H + (Kb @ H) / n  (single launch, XCD-swizzled 1-D grid)
    attn_v7<<<dim3(17 * 5 * NB), 256, 0, stream>>>(Kb, Hbt, H, out);
}